// Round 1
// baseline (2059.888 us; speedup 1.0000x reference)
//
#include <hip/hip_runtime.h>

#define N_NODES 100000
#define N_EDGES 1600000
#define FEAT 128

// ---------------- CSR build ----------------

__global__ __launch_bounds__(256) void hist_kernel(const int* __restrict__ dst,
                                                   int* __restrict__ degi) {
    int e = blockIdx.x * 256 + threadIdx.x;
    if (e < N_EDGES) atomicAdd(&degi[dst[e]], 1);
}

// per-chunk (1024 elems) totals
__global__ __launch_bounds__(256) void scanA_kernel(const int* __restrict__ degi,
                                                    int* __restrict__ sums) {
    int t = threadIdx.x;
    int base = blockIdx.x * 1024 + t * 4;
    int s = 0;
#pragma unroll
    for (int j = 0; j < 4; ++j) {
        int idx = base + j;
        if (idx < N_NODES) s += degi[idx];
    }
    __shared__ int red[256];
    red[t] = s;
    __syncthreads();
    for (int off = 128; off > 0; off >>= 1) {
        if (t < off) red[t] += red[t + off];
        __syncthreads();
    }
    if (t == 0) sums[blockIdx.x] = red[0];
}

// exclusive scan of chunk totals (single block, Hillis-Steele)
__global__ __launch_bounds__(128) void scanB_kernel(const int* __restrict__ sums,
                                                    int* __restrict__ chunkOff,
                                                    int nChunks) {
    int t = threadIdx.x;
    __shared__ int sc[128];
    int v = (t < nChunks) ? sums[t] : 0;
    sc[t] = v;
    __syncthreads();
    for (int off = 1; off < 128; off <<= 1) {
        int x = sc[t];
        int y = (t >= off) ? sc[t - off] : 0;
        __syncthreads();
        sc[t] = x + y;
        __syncthreads();
    }
    if (t < nChunks) chunkOff[t] = sc[t] - v;
}

// within-chunk exclusive scan + chunk offset -> row[]
__global__ __launch_bounds__(256) void scanC_kernel(const int* __restrict__ degi,
                                                    const int* __restrict__ chunkOff,
                                                    int* __restrict__ row) {
    int t = threadIdx.x;
    int base = blockIdx.x * 1024 + t * 4;
    int vals[4];
    int s = 0;
#pragma unroll
    for (int j = 0; j < 4; ++j) {
        int idx = base + j;
        vals[j] = (idx < N_NODES) ? degi[idx] : 0;
        s += vals[j];
    }
    __shared__ int sc[256];
    sc[t] = s;
    __syncthreads();
    for (int off = 1; off < 256; off <<= 1) {
        int x = sc[t];
        int y = (t >= off) ? sc[t - off] : 0;
        __syncthreads();
        sc[t] = x + y;
        __syncthreads();
    }
    int run = chunkOff[blockIdx.x] + sc[t] - s;  // exclusive prefix for this thread
#pragma unroll
    for (int j = 0; j < 4; ++j) {
        int idx = base + j;
        if (idx < N_NODES) {
            row[idx] = run;
            run += vals[j];
        }
    }
    if (blockIdx.x == 0 && t == 0) row[N_NODES] = N_EDGES;
}

__global__ __launch_bounds__(256) void fill_kernel(const int* __restrict__ src,
                                                   const int* __restrict__ dst,
                                                   int* __restrict__ cursor,
                                                   int* __restrict__ col) {
    int e = blockIdx.x * 256 + threadIdx.x;
    if (e < N_EDGES) {
        int pos = atomicAdd(&cursor[dst[e]], 1);
        col[pos] = src[e];
    }
}

// ---------------- aggregation: agg[v] = sum_{e in CSR[v]} h[col[e]] ----------------
// 32 lanes per node, each lane owns a float4 feature chunk. Fully writes agg.

__global__ __launch_bounds__(256) void agg_kernel(const float* __restrict__ h,
                                                  const int* __restrict__ row,
                                                  const int* __restrict__ col,
                                                  float* __restrict__ agg) {
    int t = blockIdx.x * 256 + threadIdx.x;
    int v = t >> 5;
    int c = t & 31;
    if (v >= N_NODES) return;
    int beg = row[v], end = row[v + 1];
    float ax = 0.f, ay = 0.f, az = 0.f, aw = 0.f;
    for (int i = beg; i < end; ++i) {
        int s = col[i];  // broadcast within the 32-lane group
        const float4 hv = *(const float4*)(h + (size_t)s * FEAT + c * 4);
        ax += hv.x; ay += hv.y; az += hv.z; aw += hv.w;
    }
    float4 o;
    o.x = ax; o.y = ay; o.z = az; o.w = aw;
    *(float4*)(agg + (size_t)v * FEAT + c * 4) = o;
}

// ---------------- combine: out = act(h@Ws^T + (agg/deg)@Wn^T + b) ----------------
// 64 nodes x 64 outputs per block; K-tiles of 32 in LDS (pad row to 36 floats);
// 4x4 register tile per thread; deg-normalization folded into agg staging.

__global__ __launch_bounds__(256) void combine_kernel(
    const float* __restrict__ h, const float* __restrict__ agg,
    const int* __restrict__ degi,
    const float* __restrict__ wself, const float* __restrict__ wneigh,
    const float* __restrict__ bias,
    float* __restrict__ out, int OUT, int doRelu) {
    __shared__ __align__(16) float hT[64][36];
    __shared__ __align__(16) float aT[64][36];
    __shared__ __align__(16) float sT[64][36];
    __shared__ __align__(16) float nT[64][36];
    int tid = threadIdx.x;
    int v0 = blockIdx.x * 64;
    int o0 = blockIdx.y * 64;
    float acc[4][4];
#pragma unroll
    for (int i = 0; i < 4; ++i)
#pragma unroll
        for (int j = 0; j < 4; ++j) acc[i][j] = 0.f;

    int sr = tid >> 3;         // 0..31 staging row
    int sc4 = (tid & 7) * 4;   // 0..28 staging col (float4)
    int tx = tid & 15, ty = tid >> 4;

    for (int k0 = 0; k0 < FEAT; k0 += 32) {
        __syncthreads();
#pragma unroll
        for (int rr = 0; rr < 2; ++rr) {
            int r = sr + rr * 32;
            int v = v0 + r;
            if (v >= N_NODES) v = N_NODES - 1;  // clamp; stores are guarded later
            float4 hv = *(const float4*)(h + (size_t)v * FEAT + k0 + sc4);
            float4 av = *(const float4*)(agg + (size_t)v * FEAT + k0 + sc4);
            int d = degi[v];
            float invd = 1.0f / (float)(d > 0 ? d : 1);
            av.x *= invd; av.y *= invd; av.z *= invd; av.w *= invd;
            *(float4*)&hT[r][sc4] = hv;
            *(float4*)&aT[r][sc4] = av;
            int o = o0 + r;
            float4 wsv = make_float4(0.f, 0.f, 0.f, 0.f);
            float4 wnv = make_float4(0.f, 0.f, 0.f, 0.f);
            if (o < OUT) {
                wsv = *(const float4*)(wself + (size_t)o * FEAT + k0 + sc4);
                wnv = *(const float4*)(wneigh + (size_t)o * FEAT + k0 + sc4);
            }
            *(float4*)&sT[r][sc4] = wsv;
            *(float4*)&nT[r][sc4] = wnv;
        }
        __syncthreads();
#pragma unroll
        for (int kk = 0; kk < 32; kk += 4) {
            float4 hv[4], av[4], s4[4], n4[4];
#pragma unroll
            for (int i = 0; i < 4; ++i) {
                hv[i] = *(const float4*)&hT[ty * 4 + i][kk];
                av[i] = *(const float4*)&aT[ty * 4 + i][kk];
            }
#pragma unroll
            for (int j = 0; j < 4; ++j) {
                s4[j] = *(const float4*)&sT[tx * 4 + j][kk];
                n4[j] = *(const float4*)&nT[tx * 4 + j][kk];
            }
#pragma unroll
            for (int i = 0; i < 4; ++i)
#pragma unroll
                for (int j = 0; j < 4; ++j) {
                    acc[i][j] += hv[i].x * s4[j].x + hv[i].y * s4[j].y +
                                 hv[i].z * s4[j].z + hv[i].w * s4[j].w +
                                 av[i].x * n4[j].x + av[i].y * n4[j].y +
                                 av[i].z * n4[j].z + av[i].w * n4[j].w;
                }
        }
    }
#pragma unroll
    for (int i = 0; i < 4; ++i) {
        int v = v0 + ty * 4 + i;
        if (v >= N_NODES) continue;
#pragma unroll
        for (int j = 0; j < 4; ++j) {
            int o = o0 + tx * 4 + j;
            if (o >= OUT) continue;
            float r = acc[i][j] + bias[o];
            if (doRelu) r = fmaxf(r, 0.f);
            out[(size_t)v * OUT + o] = r;
        }
    }
}

// ---------------- launch ----------------

static inline size_t align256(size_t x) { return (x + 255) & ~(size_t)255; }

extern "C" void kernel_launch(void* const* d_in, const int* in_sizes, int n_in,
                              void* d_out, int out_size, void* d_ws, size_t ws_size,
                              hipStream_t stream) {
    const float* x = (const float*)d_in[0];
    const int* src = (const int*)d_in[1];
    const int* dst = (const int*)d_in[2];
    const float* ws1 = (const float*)d_in[3];
    const float* wn1 = (const float*)d_in[4];
    const float* b1 = (const float*)d_in[5];
    const float* ws2 = (const float*)d_in[6];
    const float* wn2 = (const float*)d_in[7];
    const float* b2 = (const float*)d_in[8];
    const float* ws3 = (const float*)d_in[9];
    const float* wn3 = (const float*)d_in[10];
    const float* b3 = (const float*)d_in[11];
    const float* ws4 = (const float*)d_in[12];
    const float* wn4 = (const float*)d_in[13];
    const float* b4 = (const float*)d_in[14];
    float* out = (float*)d_out;

    char* base = (char*)d_ws;
    size_t off = 0;
    auto alloc = [&](size_t bytes) -> void* {
        void* p = base + off;
        off = align256(off + bytes);
        return p;
    };
    int* degi = (int*)alloc((size_t)N_NODES * 4);
    int* row = (int*)alloc((size_t)(N_NODES + 1) * 4);
    int* cursor = (int*)alloc((size_t)N_NODES * 4);
    int* sums = (int*)alloc(128 * 4);
    int* coff = (int*)alloc(128 * 4);
    int* col = (int*)alloc((size_t)N_EDGES * 4);
    float* bufA = (float*)alloc((size_t)N_NODES * FEAT * 4);
    float* bufB = (float*)alloc((size_t)N_NODES * FEAT * 4);
    float* agg = (float*)alloc((size_t)N_NODES * FEAT * 4);
    (void)ws_size;

    // CSR build (fresh every call; ws is poisoned between calls)
    hipMemsetAsync(degi, 0, (size_t)N_NODES * 4, stream);
    hist_kernel<<<(N_EDGES + 255) / 256, 256, 0, stream>>>(dst, degi);
    int nChunks = (N_NODES + 1023) / 1024;  // 98
    scanA_kernel<<<nChunks, 256, 0, stream>>>(degi, sums);
    scanB_kernel<<<1, 128, 0, stream>>>(sums, coff, nChunks);
    scanC_kernel<<<nChunks, 256, 0, stream>>>(degi, coff, row);
    hipMemcpyAsync(cursor, row, (size_t)N_NODES * 4, hipMemcpyDeviceToDevice, stream);
    fill_kernel<<<(N_EDGES + 255) / 256, 256, 0, stream>>>(src, dst, cursor, col);

    dim3 cgrid128((N_NODES + 63) / 64, 2);
    dim3 cgrid40((N_NODES + 63) / 64, 1);
    int aggGrid = ((size_t)N_NODES * 32 + 255) / 256;

    // layer 1: x -> bufA
    agg_kernel<<<aggGrid, 256, 0, stream>>>(x, row, col, agg);
    combine_kernel<<<cgrid128, 256, 0, stream>>>(x, agg, degi, ws1, wn1, b1, bufA, 128, 1);
    // layer 2: bufA -> bufB
    agg_kernel<<<aggGrid, 256, 0, stream>>>(bufA, row, col, agg);
    combine_kernel<<<cgrid128, 256, 0, stream>>>(bufA, agg, degi, ws2, wn2, b2, bufB, 128, 1);
    // layer 3: bufB -> bufA
    agg_kernel<<<aggGrid, 256, 0, stream>>>(bufB, row, col, agg);
    combine_kernel<<<cgrid128, 256, 0, stream>>>(bufB, agg, degi, ws3, wn3, b3, bufA, 128, 1);
    // layer 4: bufA -> out (C=40, no relu)
    agg_kernel<<<aggGrid, 256, 0, stream>>>(bufA, row, col, agg);
    combine_kernel<<<cgrid40, 256, 0, stream>>>(bufA, agg, degi, ws4, wn4, b4, out, 40, 0);
}

// Round 2
// 1033.815 us; speedup vs baseline: 1.9925x; 1.9925x over previous
//
#include <hip/hip_runtime.h>

#define N_NODES 100000
#define N_EDGES 1600000
#define FEAT 128
#define PAD 40

typedef short bf16x8 __attribute__((ext_vector_type(8)));
typedef float f32x4 __attribute__((ext_vector_type(4)));

__device__ __forceinline__ ushort f2bf(float x) {
    union { float f; unsigned int u; } v; v.f = x;
    unsigned int u = v.u;
    return (ushort)((u + 0x7fffu + ((u >> 16) & 1u)) >> 16);  // RNE
}
__device__ __forceinline__ float bf2f(ushort h) {
    union { float f; unsigned int u; } v; v.u = ((unsigned int)h) << 16;
    return v.f;
}
__device__ __forceinline__ void split4(float4 x, ushort4& hi, ushort4& lo) {
    hi.x = f2bf(x.x); lo.x = f2bf(x.x - bf2f(hi.x));
    hi.y = f2bf(x.y); lo.y = f2bf(x.y - bf2f(hi.y));
    hi.z = f2bf(x.z); lo.z = f2bf(x.z - bf2f(hi.z));
    hi.w = f2bf(x.w); lo.w = f2bf(x.w - bf2f(hi.w));
}

#define MFMA(a, b, c) __builtin_amdgcn_mfma_f32_16x16x32_bf16((a), (b), (c), 0, 0, 0)

// ---------------- CSR build ----------------

__global__ __launch_bounds__(256) void hist_kernel(const int* __restrict__ dst,
                                                   int* __restrict__ degi) {
    int e = blockIdx.x * 256 + threadIdx.x;
    if (e < N_EDGES) atomicAdd(&degi[dst[e]], 1);
}

__global__ __launch_bounds__(256) void scanA_kernel(const int* __restrict__ degi,
                                                    int* __restrict__ sums) {
    int t = threadIdx.x;
    int base = blockIdx.x * 1024 + t * 4;
    int s = 0;
#pragma unroll
    for (int j = 0; j < 4; ++j) {
        int idx = base + j;
        if (idx < N_NODES) s += degi[idx];
    }
    __shared__ int red[256];
    red[t] = s;
    __syncthreads();
    for (int off = 128; off > 0; off >>= 1) {
        if (t < off) red[t] += red[t + off];
        __syncthreads();
    }
    if (t == 0) sums[blockIdx.x] = red[0];
}

__global__ __launch_bounds__(128) void scanB_kernel(const int* __restrict__ sums,
                                                    int* __restrict__ chunkOff,
                                                    int nChunks) {
    int t = threadIdx.x;
    __shared__ int sc[128];
    int v = (t < nChunks) ? sums[t] : 0;
    sc[t] = v;
    __syncthreads();
    for (int off = 1; off < 128; off <<= 1) {
        int x = sc[t];
        int y = (t >= off) ? sc[t - off] : 0;
        __syncthreads();
        sc[t] = x + y;
        __syncthreads();
    }
    if (t < nChunks) chunkOff[t] = sc[t] - v;
}

__global__ __launch_bounds__(256) void scanC_kernel(const int* __restrict__ degi,
                                                    const int* __restrict__ chunkOff,
                                                    int* __restrict__ row) {
    int t = threadIdx.x;
    int base = blockIdx.x * 1024 + t * 4;
    int vals[4];
    int s = 0;
#pragma unroll
    for (int j = 0; j < 4; ++j) {
        int idx = base + j;
        vals[j] = (idx < N_NODES) ? degi[idx] : 0;
        s += vals[j];
    }
    __shared__ int sc[256];
    sc[t] = s;
    __syncthreads();
    for (int off = 1; off < 256; off <<= 1) {
        int x = sc[t];
        int y = (t >= off) ? sc[t - off] : 0;
        __syncthreads();
        sc[t] = x + y;
        __syncthreads();
    }
    int run = chunkOff[blockIdx.x] + sc[t] - s;
#pragma unroll
    for (int j = 0; j < 4; ++j) {
        int idx = base + j;
        if (idx < N_NODES) {
            row[idx] = run;
            run += vals[j];
        }
    }
    if (blockIdx.x == 0 && t == 0) row[N_NODES] = N_EDGES;
}

__global__ __launch_bounds__(256) void fill_kernel(const int* __restrict__ src,
                                                   const int* __restrict__ dst,
                                                   int* __restrict__ cursor,
                                                   int* __restrict__ col) {
    int e = blockIdx.x * 256 + threadIdx.x;
    if (e < N_EDGES) {
        int pos = atomicAdd(&cursor[dst[e]], 1);
        col[pos] = src[e];
    }
}

// ---------------- aggregation ----------------

__global__ __launch_bounds__(256) void agg_kernel(const float* __restrict__ h,
                                                  const int* __restrict__ row,
                                                  const int* __restrict__ col,
                                                  float* __restrict__ agg) {
    int t = blockIdx.x * 256 + threadIdx.x;
    int v = t >> 5;
    int c = t & 31;
    if (v >= N_NODES) return;
    int beg = row[v], end = row[v + 1];
    float ax = 0.f, ay = 0.f, az = 0.f, aw = 0.f;
    for (int i = beg; i < end; ++i) {
        int s = col[i];
        const float4 hv = *(const float4*)(h + (size_t)s * FEAT + c * 4);
        ax += hv.x; ay += hv.y; az += hv.z; aw += hv.w;
    }
    float4 o;
    o.x = ax; o.y = ay; o.z = az; o.w = aw;
    *(float4*)(agg + (size_t)v * FEAT + c * 4) = o;
}

// ---------------- combine: bf16-split MFMA ----------------
// out[v][o] = act( h[v]@Ws[o] + (agg[v]/deg[v])@Wn[o] + b[o] )
// Per block: 64 nodes x OUT(<=128) outputs. fp32 -> (hi,lo) bf16 split in LDS,
// 3-MFMA products (hi*hi + hi*lo + lo*hi), both GEMMs share one accumulator.
// Rows padded to 40 bf16 (80 B): fragment reads land 2 lanes/bank (free),
// 16B-aligned for ds_read_b128.

__global__ __launch_bounds__(256) void combine_mfma_kernel(
    const float* __restrict__ h, const float* __restrict__ agg,
    const int* __restrict__ degi,
    const float* __restrict__ wself, const float* __restrict__ wneigh,
    const float* __restrict__ bias,
    float* __restrict__ out, int OUT, int doRelu) {
    __shared__ __align__(16) ushort hHi[64][PAD];
    __shared__ __align__(16) ushort hLo[64][PAD];
    __shared__ __align__(16) ushort aHi[64][PAD];
    __shared__ __align__(16) ushort aLo[64][PAD];
    __shared__ __align__(16) ushort sHi[128][PAD];
    __shared__ __align__(16) ushort sLo[128][PAD];
    __shared__ __align__(16) ushort nHi[128][PAD];
    __shared__ __align__(16) ushort nLo[128][PAD];

    int tid = threadIdx.x;
    int lane = tid & 63;
    int w = tid >> 6;
    int v0 = blockIdx.x * 64;

    // node/agg staging: 4 threads per row, 8 floats each
    int ar = tid >> 2;
    int ac = (tid & 3) * 8;
    int av = v0 + ar;
    if (av >= N_NODES) av = N_NODES - 1;  // clamp; stores guarded below
    int d = degi[av];
    float invd = 1.0f / (float)(d > 0 ? d : 1);

    // weight staging: 2 threads per row, 16 floats each
    int wr = tid >> 1;
    int wc = (tid & 1) * 16;
    bool wvalid = wr < OUT;

    f32x4 acc[4][2];
#pragma unroll
    for (int mt = 0; mt < 4; ++mt)
#pragma unroll
        for (int nt = 0; nt < 2; ++nt) acc[mt][nt] = (f32x4)(0.f);

    int nb = w * 32;              // wave's output-col base
    bool waveActive = nb < OUT;   // wave-uniform
    int frow = lane & 15;
    int fcol = (lane >> 4) * 8;

    for (int k0 = 0; k0 < FEAT; k0 += 32) {
        // ---- stage + split ----
        {
            const float* hp = h + (size_t)av * FEAT + k0 + ac;
            const float* ap = agg + (size_t)av * FEAT + k0 + ac;
            float4 hv0 = *(const float4*)(hp);
            float4 hv1 = *(const float4*)(hp + 4);
            float4 av0 = *(const float4*)(ap);
            float4 av1 = *(const float4*)(ap + 4);
            av0.x *= invd; av0.y *= invd; av0.z *= invd; av0.w *= invd;
            av1.x *= invd; av1.y *= invd; av1.z *= invd; av1.w *= invd;
            ushort4 hi, lo;
            split4(hv0, hi, lo);
            *(ushort4*)&hHi[ar][ac] = hi; *(ushort4*)&hLo[ar][ac] = lo;
            split4(hv1, hi, lo);
            *(ushort4*)&hHi[ar][ac + 4] = hi; *(ushort4*)&hLo[ar][ac + 4] = lo;
            split4(av0, hi, lo);
            *(ushort4*)&aHi[ar][ac] = hi; *(ushort4*)&aLo[ar][ac] = lo;
            split4(av1, hi, lo);
            *(ushort4*)&aHi[ar][ac + 4] = hi; *(ushort4*)&aLo[ar][ac + 4] = lo;

            const float* sp = wself + (size_t)wr * FEAT + k0 + wc;
            const float* np = wneigh + (size_t)wr * FEAT + k0 + wc;
#pragma unroll
            for (int q = 0; q < 4; ++q) {
                float4 sv = make_float4(0.f, 0.f, 0.f, 0.f);
                float4 nv = make_float4(0.f, 0.f, 0.f, 0.f);
                if (wvalid) { sv = *(const float4*)(sp + q * 4); nv = *(const float4*)(np + q * 4); }
                split4(sv, hi, lo);
                *(ushort4*)&sHi[wr][wc + q * 4] = hi; *(ushort4*)&sLo[wr][wc + q * 4] = lo;
                split4(nv, hi, lo);
                *(ushort4*)&nHi[wr][wc + q * 4] = hi; *(ushort4*)&nLo[wr][wc + q * 4] = lo;
            }
        }
        __syncthreads();
        // ---- MFMA ----
        if (waveActive) {
            bf16x8 bsHi[2], bsLo[2], bnHi[2], bnLo[2];
#pragma unroll
            for (int nt = 0; nt < 2; ++nt) {
                int r = nb + nt * 16 + frow;
                bsHi[nt] = *(const bf16x8*)&sHi[r][fcol];
                bsLo[nt] = *(const bf16x8*)&sLo[r][fcol];
                bnHi[nt] = *(const bf16x8*)&nHi[r][fcol];
                bnLo[nt] = *(const bf16x8*)&nLo[r][fcol];
            }
#pragma unroll
            for (int mt = 0; mt < 4; ++mt) {
                int m = mt * 16 + frow;
                bf16x8 ahHi = *(const bf16x8*)&hHi[m][fcol];
                bf16x8 ahLo = *(const bf16x8*)&hLo[m][fcol];
                bf16x8 aaHi = *(const bf16x8*)&aHi[m][fcol];
                bf16x8 aaLo = *(const bf16x8*)&aLo[m][fcol];
#pragma unroll
                for (int nt = 0; nt < 2; ++nt) {
                    f32x4 c = acc[mt][nt];
                    c = MFMA(ahHi, bsHi[nt], c);
                    c = MFMA(ahLo, bsHi[nt], c);
                    c = MFMA(ahHi, bsLo[nt], c);
                    c = MFMA(aaHi, bnHi[nt], c);
                    c = MFMA(aaLo, bnHi[nt], c);
                    c = MFMA(aaHi, bnLo[nt], c);
                    acc[mt][nt] = c;
                }
            }
        }
        __syncthreads();
    }

    // ---- epilogue: D layout col=lane&15, row=(lane>>4)*4+i ----
    if (waveActive) {
#pragma unroll
        for (int nt = 0; nt < 2; ++nt) {
            int colo = nb + nt * 16 + (lane & 15);
            if (colo >= OUT) continue;
            float b = bias[colo];
#pragma unroll
            for (int mt = 0; mt < 4; ++mt) {
#pragma unroll
                for (int i = 0; i < 4; ++i) {
                    int v = v0 + mt * 16 + (lane >> 4) * 4 + i;
                    if (v >= N_NODES) continue;
                    float r = acc[mt][nt][i] + b;
                    if (doRelu) r = fmaxf(r, 0.f);
                    out[(size_t)v * OUT + colo] = r;
                }
            }
        }
    }
}

// ---------------- launch ----------------

static inline size_t align256(size_t x) { return (x + 255) & ~(size_t)255; }

extern "C" void kernel_launch(void* const* d_in, const int* in_sizes, int n_in,
                              void* d_out, int out_size, void* d_ws, size_t ws_size,
                              hipStream_t stream) {
    const float* x = (const float*)d_in[0];
    const int* src = (const int*)d_in[1];
    const int* dst = (const int*)d_in[2];
    const float* ws1 = (const float*)d_in[3];
    const float* wn1 = (const float*)d_in[4];
    const float* b1 = (const float*)d_in[5];
    const float* ws2 = (const float*)d_in[6];
    const float* wn2 = (const float*)d_in[7];
    const float* b2 = (const float*)d_in[8];
    const float* ws3 = (const float*)d_in[9];
    const float* wn3 = (const float*)d_in[10];
    const float* b3 = (const float*)d_in[11];
    const float* ws4 = (const float*)d_in[12];
    const float* wn4 = (const float*)d_in[13];
    const float* b4 = (const float*)d_in[14];
    float* out = (float*)d_out;

    char* base = (char*)d_ws;
    size_t off = 0;
    auto alloc = [&](size_t bytes) -> void* {
        void* p = base + off;
        off = align256(off + bytes);
        return p;
    };
    int* degi = (int*)alloc((size_t)N_NODES * 4);
    int* row = (int*)alloc((size_t)(N_NODES + 1) * 4);
    int* cursor = (int*)alloc((size_t)N_NODES * 4);
    int* sums = (int*)alloc(128 * 4);
    int* coff = (int*)alloc(128 * 4);
    int* col = (int*)alloc((size_t)N_EDGES * 4);
    float* bufA = (float*)alloc((size_t)N_NODES * FEAT * 4);
    float* bufB = (float*)alloc((size_t)N_NODES * FEAT * 4);
    float* agg = (float*)alloc((size_t)N_NODES * FEAT * 4);
    (void)ws_size;

    hipMemsetAsync(degi, 0, (size_t)N_NODES * 4, stream);
    hist_kernel<<<(N_EDGES + 255) / 256, 256, 0, stream>>>(dst, degi);
    int nChunks = (N_NODES + 1023) / 1024;  // 98
    scanA_kernel<<<nChunks, 256, 0, stream>>>(degi, sums);
    scanB_kernel<<<1, 128, 0, stream>>>(sums, coff, nChunks);
    scanC_kernel<<<nChunks, 256, 0, stream>>>(degi, coff, row);
    hipMemcpyAsync(cursor, row, (size_t)N_NODES * 4, hipMemcpyDeviceToDevice, stream);
    fill_kernel<<<(N_EDGES + 255) / 256, 256, 0, stream>>>(src, dst, cursor, col);

    int cgrid = (N_NODES + 63) / 64;  // 1563
    int aggGrid = ((size_t)N_NODES * 32 + 255) / 256;

    agg_kernel<<<aggGrid, 256, 0, stream>>>(x, row, col, agg);
    combine_mfma_kernel<<<cgrid, 256, 0, stream>>>(x, agg, degi, ws1, wn1, b1, bufA, 128, 1);
    agg_kernel<<<aggGrid, 256, 0, stream>>>(bufA, row, col, agg);
    combine_mfma_kernel<<<cgrid, 256, 0, stream>>>(bufA, agg, degi, ws2, wn2, b2, bufB, 128, 1);
    agg_kernel<<<aggGrid, 256, 0, stream>>>(bufB, row, col, agg);
    combine_mfma_kernel<<<cgrid, 256, 0, stream>>>(bufB, agg, degi, ws3, wn3, b3, bufA, 128, 1);
    agg_kernel<<<aggGrid, 256, 0, stream>>>(bufA, row, col, agg);
    combine_mfma_kernel<<<cgrid, 256, 0, stream>>>(bufA, agg, degi, ws4, wn4, b4, out, 40, 0);
}

// Round 3
// 819.838 us; speedup vs baseline: 2.5126x; 1.2610x over previous
//
#include <hip/hip_runtime.h>

#define N_NODES 100000
#define N_EDGES 1600000
#define FEAT 128

typedef short bf16x8 __attribute__((ext_vector_type(8)));
typedef float f32x4 __attribute__((ext_vector_type(4)));

__device__ __forceinline__ ushort f2bf(float x) {
    union { float f; unsigned int u; } v; v.f = x;
    unsigned int u = v.u;
    return (ushort)((u + 0x7fffu + ((u >> 16) & 1u)) >> 16);  // RNE
}
__device__ __forceinline__ float bf2f(ushort h) {
    union { float f; unsigned int u; } v; v.u = ((unsigned int)h) << 16;
    return v.f;
}

#define MFMA(a, b, c) __builtin_amdgcn_mfma_f32_16x16x32_bf16((a), (b), (c), 0, 0, 0)

// ---------------- CSR build ----------------

__global__ __launch_bounds__(256) void hist_kernel(const int* __restrict__ dst,
                                                   int* __restrict__ degi) {
    int e = blockIdx.x * 256 + threadIdx.x;
    if (e < N_EDGES) atomicAdd(&degi[dst[e]], 1);
}

__global__ __launch_bounds__(256) void scanA_kernel(const int* __restrict__ degi,
                                                    int* __restrict__ sums) {
    int t = threadIdx.x;
    int base = blockIdx.x * 1024 + t * 4;
    int s = 0;
#pragma unroll
    for (int j = 0; j < 4; ++j) {
        int idx = base + j;
        if (idx < N_NODES) s += degi[idx];
    }
    __shared__ int red[256];
    red[t] = s;
    __syncthreads();
    for (int off = 128; off > 0; off >>= 1) {
        if (t < off) red[t] += red[t + off];
        __syncthreads();
    }
    if (t == 0) sums[blockIdx.x] = red[0];
}

__global__ __launch_bounds__(128) void scanB_kernel(const int* __restrict__ sums,
                                                    int* __restrict__ chunkOff,
                                                    int nChunks) {
    int t = threadIdx.x;
    __shared__ int sc[128];
    int v = (t < nChunks) ? sums[t] : 0;
    sc[t] = v;
    __syncthreads();
    for (int off = 1; off < 128; off <<= 1) {
        int x = sc[t];
        int y = (t >= off) ? sc[t - off] : 0;
        __syncthreads();
        sc[t] = x + y;
        __syncthreads();
    }
    if (t < nChunks) chunkOff[t] = sc[t] - v;
}

__global__ __launch_bounds__(256) void scanC_kernel(const int* __restrict__ degi,
                                                    const int* __restrict__ chunkOff,
                                                    int* __restrict__ row) {
    int t = threadIdx.x;
    int base = blockIdx.x * 1024 + t * 4;
    int vals[4];
    int s = 0;
#pragma unroll
    for (int j = 0; j < 4; ++j) {
        int idx = base + j;
        vals[j] = (idx < N_NODES) ? degi[idx] : 0;
        s += vals[j];
    }
    __shared__ int sc[256];
    sc[t] = s;
    __syncthreads();
    for (int off = 1; off < 256; off <<= 1) {
        int x = sc[t];
        int y = (t >= off) ? sc[t - off] : 0;
        __syncthreads();
        sc[t] = x + y;
        __syncthreads();
    }
    int run = chunkOff[blockIdx.x] + sc[t] - s;
#pragma unroll
    for (int j = 0; j < 4; ++j) {
        int idx = base + j;
        if (idx < N_NODES) {
            row[idx] = run;
            run += vals[j];
        }
    }
    if (blockIdx.x == 0 && t == 0) row[N_NODES] = N_EDGES;
}

__global__ __launch_bounds__(256) void fill_kernel(const int* __restrict__ src,
                                                   const int* __restrict__ dst,
                                                   int* __restrict__ cursor,
                                                   int* __restrict__ col) {
    int e = blockIdx.x * 256 + threadIdx.x;
    if (e < N_EDGES) {
        int pos = atomicAdd(&cursor[dst[e]], 1);
        col[pos] = src[e];
    }
}

// ---------------- converts ----------------

// x fp32 -> bf16, 4 elems/thread
__global__ __launch_bounds__(256) void convert_x_kernel(const float* __restrict__ x,
                                                        ushort* __restrict__ xb) {
    int idx = (blockIdx.x * 256 + threadIdx.x) * 4;
    if (idx >= N_NODES * FEAT) return;
    float4 v = *(const float4*)(x + idx);
    ushort4 o;
    o.x = f2bf(v.x); o.y = f2bf(v.y); o.z = f2bf(v.z); o.w = f2bf(v.w);
    *(ushort4*)(xb + idx) = o;
}

// weights fp32 -> (hi, lo) bf16 planes, zero-padded to 128 rows.
// mat order: ws1,wn1,ws2,wn2,ws3,wn3,ws4,wn4; mat m occupies wp + m*32768
// (hi plane 16384 ushorts, then lo plane).
__global__ __launch_bounds__(128) void convert_w_kernel(
    const float* w0, const float* w1, const float* w2, const float* w3,
    const float* w4, const float* w5, const float* w6, const float* w7,
    ushort* __restrict__ wp) {
    int m = blockIdx.y;
    int r = blockIdx.x;
    int c = threadIdx.x;
    const float* src;
    switch (m) {
        case 0: src = w0; break; case 1: src = w1; break;
        case 2: src = w2; break; case 3: src = w3; break;
        case 4: src = w4; break; case 5: src = w5; break;
        case 6: src = w6; break; default: src = w7; break;
    }
    int rows = (m >= 6) ? 40 : 128;
    float val = (r < rows) ? src[r * FEAT + c] : 0.f;
    ushort hi = f2bf(val);
    ushort lo = f2bf(val - bf2f(hi));
    wp[(size_t)m * 32768 + r * FEAT + c] = hi;
    wp[(size_t)m * 32768 + 16384 + r * FEAT + c] = lo;
}

// ---------------- aggregation (bf16 in, normalized bf16 out) ----------------
// One 64-lane wave per node; each lane owns one bf16x2 feature pair (4 B).

__global__ __launch_bounds__(256) void agg_kernel(const ushort* __restrict__ hb,
                                                  const int* __restrict__ row,
                                                  const int* __restrict__ col,
                                                  ushort* __restrict__ aggB) {
    int t = blockIdx.x * 256 + threadIdx.x;
    int v = t >> 6;
    int lane = t & 63;
    if (v >= N_NODES) return;
    int beg = row[v], end = row[v + 1];
    const unsigned int* base = (const unsigned int*)hb;  // 64 uints per node row
    float s0 = 0.f, s1 = 0.f;
    int i = beg;
    for (; i + 4 <= end; i += 4) {
        int c0 = col[i], c1 = col[i + 1], c2 = col[i + 2], c3 = col[i + 3];
        unsigned int p0 = base[(size_t)c0 * 64 + lane];
        unsigned int p1 = base[(size_t)c1 * 64 + lane];
        unsigned int p2 = base[(size_t)c2 * 64 + lane];
        unsigned int p3 = base[(size_t)c3 * 64 + lane];
        s0 += bf2f((ushort)(p0 & 0xffff)); s1 += bf2f((ushort)(p0 >> 16));
        s0 += bf2f((ushort)(p1 & 0xffff)); s1 += bf2f((ushort)(p1 >> 16));
        s0 += bf2f((ushort)(p2 & 0xffff)); s1 += bf2f((ushort)(p2 >> 16));
        s0 += bf2f((ushort)(p3 & 0xffff)); s1 += bf2f((ushort)(p3 >> 16));
    }
    for (; i < end; ++i) {
        unsigned int p = base[(size_t)col[i] * 64 + lane];
        s0 += bf2f((ushort)(p & 0xffff));
        s1 += bf2f((ushort)(p >> 16));
    }
    int deg = end - beg;
    float invd = 1.0f / (float)(deg > 0 ? deg : 1);
    unsigned int o = (unsigned int)f2bf(s0 * invd) | ((unsigned int)f2bf(s1 * invd) << 16);
    ((unsigned int*)aggB)[(size_t)v * 64 + lane] = o;
}

// ---------------- combine: LDS-free bf16 MFMA ----------------
// out[v][o] = act( h[v]@Ws[o] + agg[v]@Wn[o] + b[o] ),  agg pre-normalized.
// A and B fragments for 16x16x32 bf16 are contiguous 16 B in global memory:
//   A[m][k]: m=lane&15, k=(lane>>4)*8+j  -> h row slice
//   B[n][k]: n=lane&15, k=(lane>>4)*8+j  -> weight-plane row slice
// Weights pre-split hi/lo so only h's single bf16 rounding contributes error.
// Per block: 64 nodes x (32 cols per wave). No LDS, no __syncthreads.

__global__ __launch_bounds__(256) void combine_kernel(
    const ushort* __restrict__ hb, const ushort* __restrict__ aggB,
    const ushort* __restrict__ wp,   // [sHi|sLo|nHi|nLo] planes, 16384 ushorts each
    const float* __restrict__ bias,
    float* __restrict__ outF, ushort* __restrict__ outB,
    int OUT, int doRelu) {
    int tid = threadIdx.x;
    int lane = tid & 63;
    int w = tid >> 6;
    int v0 = blockIdx.x * 64;
    int frow = lane & 15;
    int fk = (lane >> 4) * 8;
    int nb = w * 32;

    const ushort* sHi = wp;
    const ushort* sLo = wp + 16384;
    const ushort* nHi = wp + 32768;
    const ushort* nLo = wp + 49152;

    int mnode[4];
#pragma unroll
    for (int mt = 0; mt < 4; ++mt) {
        int v = v0 + mt * 16 + frow;
        mnode[mt] = v < N_NODES ? v : N_NODES - 1;
    }
    int n0 = nb + frow;
    int n1 = nb + 16 + frow;

    f32x4 acc[4][2];
#pragma unroll
    for (int mt = 0; mt < 4; ++mt)
#pragma unroll
        for (int nt = 0; nt < 2; ++nt) acc[mt][nt] = (f32x4)(0.f);

#pragma unroll
    for (int kt = 0; kt < 4; ++kt) {
        int k = kt * 32 + fk;
        bf16x8 Bs[2][2], Bn[2][2];
        Bs[0][0] = *(const bf16x8*)(sHi + n0 * FEAT + k);
        Bs[0][1] = *(const bf16x8*)(sLo + n0 * FEAT + k);
        Bn[0][0] = *(const bf16x8*)(nHi + n0 * FEAT + k);
        Bn[0][1] = *(const bf16x8*)(nLo + n0 * FEAT + k);
        Bs[1][0] = *(const bf16x8*)(sHi + n1 * FEAT + k);
        Bs[1][1] = *(const bf16x8*)(sLo + n1 * FEAT + k);
        Bn[1][0] = *(const bf16x8*)(nHi + n1 * FEAT + k);
        Bn[1][1] = *(const bf16x8*)(nLo + n1 * FEAT + k);
#pragma unroll
        for (int mt = 0; mt < 4; ++mt) {
            bf16x8 Ah = *(const bf16x8*)(hb + (size_t)mnode[mt] * FEAT + k);
            bf16x8 Aa = *(const bf16x8*)(aggB + (size_t)mnode[mt] * FEAT + k);
#pragma unroll
            for (int nt = 0; nt < 2; ++nt) {
                f32x4 c = acc[mt][nt];
                c = MFMA(Ah, Bs[nt][0], c);
                c = MFMA(Ah, Bs[nt][1], c);
                c = MFMA(Aa, Bn[nt][0], c);
                c = MFMA(Aa, Bn[nt][1], c);
                acc[mt][nt] = c;
            }
        }
    }

    // epilogue: C/D layout col=lane&15, row=(lane>>4)*4+i
#pragma unroll
    for (int nt = 0; nt < 2; ++nt) {
        int colo = nb + nt * 16 + (lane & 15);
        if (colo >= OUT) continue;
        float b = bias[colo];
#pragma unroll
        for (int mt = 0; mt < 4; ++mt) {
#pragma unroll
            for (int i = 0; i < 4; ++i) {
                int v = v0 + mt * 16 + (lane >> 4) * 4 + i;
                if (v >= N_NODES) continue;
                float r = acc[mt][nt][i] + b;
                if (doRelu) r = fmaxf(r, 0.f);
                if (outF) outF[(size_t)v * OUT + colo] = r;
                else outB[(size_t)v * FEAT + colo] = f2bf(r);
            }
        }
    }
}

// ---------------- launch ----------------

static inline size_t align256(size_t x) { return (x + 255) & ~(size_t)255; }

extern "C" void kernel_launch(void* const* d_in, const int* in_sizes, int n_in,
                              void* d_out, int out_size, void* d_ws, size_t ws_size,
                              hipStream_t stream) {
    const float* x = (const float*)d_in[0];
    const int* src = (const int*)d_in[1];
    const int* dst = (const int*)d_in[2];
    const float* ws1 = (const float*)d_in[3];
    const float* wn1 = (const float*)d_in[4];
    const float* b1 = (const float*)d_in[5];
    const float* ws2 = (const float*)d_in[6];
    const float* wn2 = (const float*)d_in[7];
    const float* b2 = (const float*)d_in[8];
    const float* ws3 = (const float*)d_in[9];
    const float* wn3 = (const float*)d_in[10];
    const float* b3 = (const float*)d_in[11];
    const float* ws4 = (const float*)d_in[12];
    const float* wn4 = (const float*)d_in[13];
    const float* b4 = (const float*)d_in[14];
    float* out = (float*)d_out;

    char* base = (char*)d_ws;
    size_t off = 0;
    auto alloc = [&](size_t bytes) -> void* {
        void* p = base + off;
        off = align256(off + bytes);
        return p;
    };
    int* degi = (int*)alloc((size_t)N_NODES * 4);
    int* row = (int*)alloc((size_t)(N_NODES + 1) * 4);
    int* cursor = (int*)alloc((size_t)N_NODES * 4);
    int* sums = (int*)alloc(128 * 4);
    int* coff = (int*)alloc(128 * 4);
    int* col = (int*)alloc((size_t)N_EDGES * 4);
    ushort* wp = (ushort*)alloc((size_t)8 * 32768 * 2);           // 512 KB weight planes
    ushort* xb = (ushort*)alloc((size_t)N_NODES * FEAT * 2);
    ushort* bufA = (ushort*)alloc((size_t)N_NODES * FEAT * 2);
    ushort* bufB = (ushort*)alloc((size_t)N_NODES * FEAT * 2);
    ushort* aggB = (ushort*)alloc((size_t)N_NODES * FEAT * 2);
    (void)ws_size;

    // converts + CSR build
    convert_x_kernel<<<(N_NODES * FEAT / 4 + 255) / 256, 256, 0, stream>>>(x, xb);
    convert_w_kernel<<<dim3(128, 8), 128, 0, stream>>>(ws1, wn1, ws2, wn2, ws3, wn3,
                                                       ws4, wn4, wp);
    hipMemsetAsync(degi, 0, (size_t)N_NODES * 4, stream);
    hist_kernel<<<(N_EDGES + 255) / 256, 256, 0, stream>>>(dst, degi);
    int nChunks = (N_NODES + 1023) / 1024;  // 98
    scanA_kernel<<<nChunks, 256, 0, stream>>>(degi, sums);
    scanB_kernel<<<1, 128, 0, stream>>>(sums, coff, nChunks);
    scanC_kernel<<<nChunks, 256, 0, stream>>>(degi, coff, row);
    hipMemcpyAsync(cursor, row, (size_t)N_NODES * 4, hipMemcpyDeviceToDevice, stream);
    fill_kernel<<<(N_EDGES + 255) / 256, 256, 0, stream>>>(src, dst, cursor, col);

    int cgrid = (N_NODES + 63) / 64;                       // 1563
    int aggGrid = ((size_t)N_NODES * 64 + 255) / 256;      // 25000

    const ushort* wp1 = wp;
    const ushort* wp2 = wp + (size_t)2 * 32768;
    const ushort* wp3 = wp + (size_t)4 * 32768;
    const ushort* wp4 = wp + (size_t)6 * 32768;

    agg_kernel<<<aggGrid, 256, 0, stream>>>(xb, row, col, aggB);
    combine_kernel<<<cgrid, 256, 0, stream>>>(xb, aggB, wp1, b1, nullptr, bufA, 128, 1);
    agg_kernel<<<aggGrid, 256, 0, stream>>>(bufA, row, col, aggB);
    combine_kernel<<<cgrid, 256, 0, stream>>>(bufA, aggB, wp2, b2, nullptr, bufB, 128, 1);
    agg_kernel<<<aggGrid, 256, 0, stream>>>(bufB, row, col, aggB);
    combine_kernel<<<cgrid, 256, 0, stream>>>(bufB, aggB, wp3, b3, nullptr, bufA, 128, 1);
    agg_kernel<<<aggGrid, 256, 0, stream>>>(bufA, row, col, aggB);
    combine_kernel<<<cgrid, 128, 0, stream>>>(bufA, aggB, wp4, b4, out, nullptr, 40, 0);
}